// Round 1
// baseline (225.769 us; speedup 1.0000x reference)
//
#include <hip/hip_runtime.h>

#define BB 64
#define SS 512
#define HH 768
#define EE 128
#define TT 4

// ---------------------------------------------------------------------------
// Kernel 1: counting-sort ent_tokens (E*T = 512 pairs) by token position s.
// Produces offsets[S+1] and entries[512] (entity index e per pair; duplicates
// preserved so multiplicity is handled by plain summation downstream).
// One block, 512 threads. Rebuilt every launch (d_ws is re-poisoned).
// ---------------------------------------------------------------------------
__global__ __launch_bounds__(SS) void build_index_kernel(
    const int* __restrict__ ent_tokens,
    int* __restrict__ offsets,    // S+1 ints
    int* __restrict__ entries) {  // E*T ints
    __shared__ int cnt[SS];
    __shared__ int scan[SS];
    __shared__ int pos[SS];
    const int tid = threadIdx.x;  // 0..511

    cnt[tid] = 0;
    __syncthreads();

    const int s = ent_tokens[tid];
    atomicAdd(&cnt[s], 1);
    __syncthreads();

    // Hillis-Steele inclusive scan of cnt -> scan
    scan[tid] = cnt[tid];
    __syncthreads();
    for (int off = 1; off < SS; off <<= 1) {
        int add = (tid >= off) ? scan[tid - off] : 0;
        __syncthreads();
        scan[tid] += add;
        __syncthreads();
    }

    const int excl = scan[tid] - cnt[tid];  // exclusive prefix for bucket tid
    offsets[tid] = excl;
    if (tid == 0) offsets[SS] = EE * TT;
    pos[tid] = excl;
    __syncthreads();

    const int p = atomicAdd(&pos[s], 1);
    entries[p] = tid >> 2;  // e = (e*T + t) / T
}

// ---------------------------------------------------------------------------
// Kernel 2: enhanced[b,s,:] = hidden[b,s,:] + sum over matching entries of
//   (type_table[type[b,e]] + conf[b,e]*conf_w + conf_b)
// One block per row (b*S+s), 192 threads x float4 = 768 floats.
// ---------------------------------------------------------------------------
__global__ __launch_bounds__(HH / 4) void enhance_kernel(
    const float* __restrict__ hidden,
    const int* __restrict__ entity_types,   // (B,E)
    const float* __restrict__ conf,         // (B,E)
    const float* __restrict__ type_table,   // (5,H)
    const float* __restrict__ conf_w,       // (H)
    const float* __restrict__ conf_b,       // (H)
    const int* __restrict__ offsets,
    const int* __restrict__ entries,
    float* __restrict__ enhanced) {
    const int row = blockIdx.x;          // b*S + s
    const int b = row >> 9;              // / 512
    const int s = row & (SS - 1);
    const int h4 = threadIdx.x;          // 0..191

    float4 acc = ((const float4*)(hidden + (size_t)row * HH))[h4];

    const int o0 = offsets[s];
    const int o1 = offsets[s + 1];
    if (o1 > o0) {
        const float4 wv = ((const float4*)conf_w)[h4];
        const float4 bv = ((const float4*)conf_b)[h4];
        for (int j = o0; j < o1; ++j) {
            const int e = entries[j];
            const int ty = entity_types[b * EE + e];
            const float c = conf[b * EE + e];
            const float4 tv = ((const float4*)(type_table + (size_t)ty * HH))[h4];
            acc.x += tv.x + fmaf(c, wv.x, bv.x);
            acc.y += tv.y + fmaf(c, wv.y, bv.y);
            acc.z += tv.z + fmaf(c, wv.z, bv.z);
            acc.w += tv.w + fmaf(c, wv.w, bv.w);
        }
    }

    ((float4*)(enhanced + (size_t)row * HH))[h4] = acc;
}

// ---------------------------------------------------------------------------
// Kernel 3: entity_embeddings[b,e,:] = mean over t of enhanced[b,ent_tokens[e,t],:]
// One block per (b*E+e), 192 threads x float4. Reads hit L2/L3 (just written).
// ---------------------------------------------------------------------------
__global__ __launch_bounds__(HH / 4) void gather_mean_kernel(
    const float* __restrict__ enhanced,
    const int* __restrict__ ent_tokens,  // (E,T)
    float* __restrict__ ee) {            // (B,E,H)
    const int be = blockIdx.x;  // b*E + e
    const int b = be >> 7;      // / 128
    const int e = be & (EE - 1);
    const int h4 = threadIdx.x;

    float4 acc = make_float4(0.f, 0.f, 0.f, 0.f);
    for (int t = 0; t < TT; ++t) {
        const int s = ent_tokens[e * TT + t];
        const float4 v =
            ((const float4*)(enhanced + ((size_t)(b * SS + s)) * HH))[h4];
        acc.x += v.x;
        acc.y += v.y;
        acc.z += v.z;
        acc.w += v.w;
    }
    float4 o;
    o.x = acc.x * 0.25f;
    o.y = acc.y * 0.25f;
    o.z = acc.z * 0.25f;
    o.w = acc.w * 0.25f;
    ((float4*)(ee + (size_t)be * HH))[h4] = o;
}

extern "C" void kernel_launch(void* const* d_in, const int* in_sizes, int n_in,
                              void* d_out, int out_size, void* d_ws,
                              size_t ws_size, hipStream_t stream) {
    const float* hidden = (const float*)d_in[0];        // (B,S,H) fp32
    const int* entity_types = (const int*)d_in[1];      // (B,E) i32
    const float* conf = (const float*)d_in[2];          // (B,E) fp32
    const int* ent_tokens = (const int*)d_in[3];        // (E,T) i32
    const float* type_table = (const float*)d_in[4];    // (5,H) fp32
    const float* conf_w = (const float*)d_in[5];        // (1,H) fp32
    const float* conf_b = (const float*)d_in[6];        // (H) fp32

    float* enhanced = (float*)d_out;                          // (B,S,H)
    float* ee = (float*)d_out + (size_t)BB * SS * HH;         // (B,E,H)

    int* offsets = (int*)d_ws;           // S+1
    int* entries = offsets + (SS + 1);   // E*T

    build_index_kernel<<<1, SS, 0, stream>>>(ent_tokens, offsets, entries);
    enhance_kernel<<<BB * SS, HH / 4, 0, stream>>>(
        hidden, entity_types, conf, type_table, conf_w, conf_b, offsets,
        entries, enhanced);
    gather_mean_kernel<<<BB * EE, HH / 4, 0, stream>>>(enhanced, ent_tokens, ee);
}